// Round 4
// baseline (200.502 us; speedup 1.0000x reference)
//
#include <hip/hip_runtime.h>
#include <cstdint>
#include <cstddef>

using bf16 = __bf16;
typedef float f32x4 __attribute__((ext_vector_type(4)));
typedef __bf16 bf16x8v __attribute__((ext_vector_type(8)));
typedef __bf16 bf16x4v __attribute__((ext_vector_type(4)));

// Problem constants: B=4, S=2048, D=1024
#define NX   8388608      // 4*2048*1024
#define NW   1048576      // 1024*1024
#define SB   2048
#define DD   1024

#define VMCNT(n) asm volatile("s_waitcnt vmcnt(" #n ")" ::: "memory")

__device__ __forceinline__ void gload_lds16(const bf16* g, bf16* l) {
    __builtin_amdgcn_global_load_lds(
        (const __attribute__((address_space(1))) void*)(g),
        (__attribute__((address_space(3))) void*)(l), 16, 0, 0);
}

// ---------------------------------------------------------------------------
// Convert fp32 inputs -> bf16 in workspace; copy biases (fp32) contiguous.
// ---------------------------------------------------------------------------
__global__ __launch_bounds__(256)
void convert_kernel(const float* __restrict__ x1,
                    const float* __restrict__ Wq, const float* __restrict__ Wk,
                    const float* __restrict__ Wv,
                    const float* __restrict__ bq, const float* __restrict__ bk,
                    const float* __restrict__ bv,
                    bf16* __restrict__ xb, bf16* __restrict__ wb,
                    float* __restrict__ biases)
{
    const int NX4 = NX / 4;
    const int NW4 = NW / 4;
    const int NMAT = NX4 + 3 * NW4;
    const int total = NMAT + 768;
    for (int i = blockIdx.x * 256 + threadIdx.x; i < total; i += gridDim.x * 256) {
        if (i < NMAT) {
            const float* src; bf16* dst; int j;
            if (i < NX4) { src = x1; dst = xb; j = i; }
            else {
                int w = (i - NX4) / NW4;
                j = (i - NX4) - w * NW4;
                src = (w == 0) ? Wq : (w == 1) ? Wk : Wv;
                dst = wb + (size_t)w * NW;
            }
            float4 f = ((const float4*)src)[j];
            bf16x4v o;
            o[0] = (bf16)f.x; o[1] = (bf16)f.y; o[2] = (bf16)f.z; o[3] = (bf16)f.w;
            ((bf16x4v*)dst)[j] = o;
        } else {
            int j = i - NMAT;
            const float* src = (j < 256) ? bq : (j < 512) ? bk : bv;
            ((float4*)biases)[j] = ((const float4*)src)[j & 255];
        }
    }
}

// ---------------------------------------------------------------------------
// 8-phase-style GEMM: C[m][n] = scale*sum_k A[m][k]*B[n][k] (+bias routing).
// BM x 256 tile, BK=64 as two 32-wide K-slices (ks), 8 waves (2M x 4N),
// 512 threads. Per tile: 4 phases (ks x mh), 2 barriers (at ks transitions),
// counted vmcnt per the FIFO ledger (never 0 except final tile).
// LDS K-half [rows][32] stored as paired-row 128B lines with slot swizzle
// slot = ((r&1)*4 + c) ^ (line&7): 16-lane frag reads hit each slot 2x (free),
// stage = linear LDS dest + inverse-permuted global source (wave-uniform ok).
// V=0: fused QKV epilogue (bias; col<1024 q, <2048 k, else v transposed)
// V=1: bf16 out scaled      V=2: f32 out
// ---------------------------------------------------------------------------
template<int V, int BM, typename OutT>
__global__ __launch_bounds__(512, 2)
void gemm8p(const bf16* __restrict__ A, const bf16* __restrict__ B,
            OutT* __restrict__ C, bf16* __restrict__ vT,
            const float* __restrict__ bias,
            int N, int K, int NXT,
            long sA, long sB, long sC, float scale)
{
    constexpr int MF = BM / 32;   // M-frags per wave (8 or 4)
    constexpr int MH = MF / 2;    // frags per mh-phase (4 or 2)
    constexpr int LA = BM / 128;  // per-thread loads per A half (2 or 1)

    __shared__ bf16 shA[2][2][BM * 32];   // [buf][ks][...]
    __shared__ bf16 shB[2][2][256 * 32];

    const int z = blockIdx.z;
    A += (size_t)z * sA; B += (size_t)z * sB; C += (size_t)z * sC;

    // T1: XCD-aware bijective swizzle (gridDim.x % 8 == 0 in all launches)
    const int nwg = gridDim.x;
    const int q8 = nwg >> 3;
    const int tile = ((int)blockIdx.x & 7) * q8 + ((int)blockIdx.x >> 3);
    const int bx = tile % NXT, by = tile / NXT;
    const int n0 = bx * 256, m0 = by * BM;

    const int tid = threadIdx.x;
    const int lane = tid & 63, wid = tid >> 6;
    const int wr = wid >> 2, wc = wid & 3;

    const bf16* Ag = A + (size_t)m0 * K;
    const bf16* Bg = B + (size_t)n0 * K;

    // stage source offsets (elements) for this thread's chunk slots
    auto chunkoff = [&](int ci) {
        const int line = ci >> 3;
        const int su = (ci & 7) ^ (line & 7);
        const int r = 2 * line + (su >> 2);
        const int c = su & 3;
        return r * K + c * 8;
    };
    const int o0 = chunkoff(tid);
    const int o1 = chunkoff(512 + tid);

    // ds_read offsets (elements within a K-half)
    const int rl = lane & 15, lg = lane >> 4;
    const int rp = rl & 1, rh = rl >> 1;
    const int lA0 = wr * (BM / 4) + rh;
    const int offA = lA0 * 64 + ((((rp << 2) | lg) ^ (lA0 & 7)) << 3);
    const int lB0 = wc * 32 + rh;
    const int offB = lB0 * 64 + ((((rp << 2) | lg) ^ (lB0 & 7)) << 3);

    f32x4 acc[MF][4];
    #pragma unroll
    for (int m = 0; m < MF; ++m)
        #pragma unroll
        for (int n = 0; n < 4; ++n) acc[m][n] = (f32x4){0.f, 0.f, 0.f, 0.f};

    const int NT = K >> 6;

    auto stageA = [&](const bf16* gk, bf16* l) {
        gload_lds16(gk + o0, l + tid * 8);
        if constexpr (LA == 2) gload_lds16(gk + o1, l + (512 + tid) * 8);
    };
    auto stageB = [&](const bf16* gk, bf16* l) {
        gload_lds16(gk + o0, l + tid * 8);
        gload_lds16(gk + o1, l + (512 + tid) * 8);
    };

    // prologue: issue order fixes the FIFO ledger
    stageA(Ag,      &shA[0][0][0]);   // t0.A.ks0
    stageB(Bg,      &shB[0][0][0]);   // t0.B.ks0
    stageA(Ag + 32, &shA[0][1][0]);   // t0.A.ks1
    stageB(Bg + 32, &shB[0][1][0]);   // t0.B.ks1
    stageA(Ag + 64, &shA[1][0][0]);   // t1.A.ks0
    stageB(Bg + 64, &shB[1][0][0]);   // t1.B.ks0

    for (int t = 0; t < NT; ++t) {
        const int buf = t & 1;
        const bool nl  = (t + 1 < NT);
        const bool nl2 = (t + 2 < NT);
        bf16x8v bfr[4], af[MH];

        // ================= p0: ks0, mh0 =================
        if (nl) { if constexpr (LA == 2) VMCNT(8); else VMCNT(6); }
        else    { if constexpr (LA == 2) VMCNT(4); else VMCNT(3); }
        __builtin_amdgcn_s_barrier();
        if (nl) stageA(Ag + (t + 1) * 64 + 32, &shA[buf ^ 1][1][0]);
        {
            const bf16* pb = &shB[buf][0][offB];
            #pragma unroll
            for (int n = 0; n < 4; ++n) bfr[n] = *(const bf16x8v*)(pb + n * 512);
            const bf16* pa = &shA[buf][0][offA];
            #pragma unroll
            for (int i = 0; i < MH; ++i) af[i] = *(const bf16x8v*)(pa + i * 512);
        }
        asm volatile("s_waitcnt lgkmcnt(0)" ::: "memory");
        __builtin_amdgcn_sched_barrier(0);
        __builtin_amdgcn_s_setprio(1);
        #pragma unroll
        for (int i = 0; i < MH; ++i)
            #pragma unroll
            for (int n = 0; n < 4; ++n)
                acc[i][n] = __builtin_amdgcn_mfma_f32_16x16x32_bf16(af[i], bfr[n], acc[i][n], 0, 0, 0);
        __builtin_amdgcn_s_setprio(0);

        // ================= p1: ks0, mh1 =================
        if (nl) stageB(Bg + (t + 1) * 64 + 32, &shB[buf ^ 1][1][0]);
        {
            const bf16* pa = &shA[buf][0][offA];
            #pragma unroll
            for (int i = 0; i < MH; ++i) af[i] = *(const bf16x8v*)(pa + (MH + i) * 512);
        }
        asm volatile("s_waitcnt lgkmcnt(0)" ::: "memory");
        __builtin_amdgcn_sched_barrier(0);
        __builtin_amdgcn_s_setprio(1);
        #pragma unroll
        for (int i = 0; i < MH; ++i)
            #pragma unroll
            for (int n = 0; n < 4; ++n)
                acc[MH + i][n] = __builtin_amdgcn_mfma_f32_16x16x32_bf16(af[i], bfr[n], acc[MH + i][n], 0, 0, 0);
        __builtin_amdgcn_s_setprio(0);

        // ================= p2: ks1, mh0 =================
        if (nl) { if constexpr (LA == 2) VMCNT(8); else VMCNT(6); }
        else    VMCNT(0);
        __builtin_amdgcn_s_barrier();
        if (nl2) stageA(Ag + (t + 2) * 64, &shA[buf][0][0]);
        {
            const bf16* pb = &shB[buf][1][offB];
            #pragma unroll
            for (int n = 0; n < 4; ++n) bfr[n] = *(const bf16x8v*)(pb + n * 512);
            const bf16* pa = &shA[buf][1][offA];
            #pragma unroll
            for (int i = 0; i < MH; ++i) af[i] = *(const bf16x8v*)(pa + i * 512);
        }
        asm volatile("s_waitcnt lgkmcnt(0)" ::: "memory");
        __builtin_amdgcn_sched_barrier(0);
        __builtin_amdgcn_s_setprio(1);
        #pragma unroll
        for (int i = 0; i < MH; ++i)
            #pragma unroll
            for (int n = 0; n < 4; ++n)
                acc[i][n] = __builtin_amdgcn_mfma_f32_16x16x32_bf16(af[i], bfr[n], acc[i][n], 0, 0, 0);
        __builtin_amdgcn_s_setprio(0);

        // ================= p3: ks1, mh1 =================
        if (nl2) stageB(Bg + (t + 2) * 64, &shB[buf][0][0]);
        {
            const bf16* pa = &shA[buf][1][offA];
            #pragma unroll
            for (int i = 0; i < MH; ++i) af[i] = *(const bf16x8v*)(pa + (MH + i) * 512);
        }
        asm volatile("s_waitcnt lgkmcnt(0)" ::: "memory");
        __builtin_amdgcn_sched_barrier(0);
        __builtin_amdgcn_s_setprio(1);
        #pragma unroll
        for (int i = 0; i < MH; ++i)
            #pragma unroll
            for (int n = 0; n < 4; ++n)
                acc[MH + i][n] = __builtin_amdgcn_mfma_f32_16x16x32_bf16(af[i], bfr[n], acc[MH + i][n], 0, 0, 0);
        __builtin_amdgcn_s_setprio(0);
    }

    // epilogue: C/D map col=lane&15, row=(lane>>4)*4+reg (m89-verified)
    const int ci = rl;
    const int ri = lg << 2;
    #pragma unroll
    for (int m = 0; m < MF; ++m) {
        const int gm = m0 + wr * (BM / 2) + m * 16 + ri;
        #pragma unroll
        for (int n = 0; n < 4; ++n) {
            const int col = n0 + wc * 64 + n * 16 + ci;
            if constexpr (V == 0) {
                const float bb = bias[col];
                if (col < 1024) {
                    #pragma unroll
                    for (int r = 0; r < 4; ++r)
                        C[(size_t)(gm + r) * 1024 + col] = (OutT)(acc[m][n][r] + bb);
                } else if (col < 2048) {
                    #pragma unroll
                    for (int r = 0; r < 4; ++r)
                        C[NX + (size_t)(gm + r) * 1024 + (col - 1024)] = (OutT)(acc[m][n][r] + bb);
                } else {
                    const int batch = gm >> 11, s = gm & 2047, d = col - 2048;
                    bf16x4v pk;
                    #pragma unroll
                    for (int r = 0; r < 4; ++r) pk[r] = (bf16)(acc[m][n][r] + bb);
                    *(bf16x4v*)&vT[((size_t)batch << 21) + ((size_t)d << 11) + s] = pk;
                }
            } else {
                #pragma unroll
                for (int r = 0; r < 4; ++r)
                    C[(size_t)(gm + r) * N + col] = (OutT)(acc[m][n][r] * scale);
            }
        }
    }
}

// ---------------------------------------------------------------------------
// Row softmax in-place over bf16 scores; rows of length 2048, 1 block/row.
// ---------------------------------------------------------------------------
__global__ __launch_bounds__(256)
void softmax_inplace(bf16* __restrict__ sc)
{
    __shared__ float red[8];
    bf16* row = sc + (size_t)blockIdx.x * 2048;
    const int t = threadIdx.x;
    const int lane = t & 63;
    const int wid = t >> 6;

    bf16x8v v = *(const bf16x8v*)(row + t * 8);
    float f[8];
    #pragma unroll
    for (int j = 0; j < 8; ++j) f[j] = (float)v[j];

    float m = f[0];
    #pragma unroll
    for (int j = 1; j < 8; ++j) m = fmaxf(m, f[j]);
    #pragma unroll
    for (int off = 32; off >= 1; off >>= 1) m = fmaxf(m, __shfl_xor(m, off));
    if (lane == 0) red[wid] = m;
    __syncthreads();
    m = fmaxf(fmaxf(red[0], red[1]), fmaxf(red[2], red[3]));

    float s = 0.f;
    #pragma unroll
    for (int j = 0; j < 8; ++j) { f[j] = __expf(f[j] - m); s += f[j]; }
    #pragma unroll
    for (int off = 32; off >= 1; off >>= 1) s += __shfl_xor(s, off);
    if (lane == 0) red[4 + wid] = s;
    __syncthreads();
    s = red[4] + red[5] + red[6] + red[7];

    const float inv = 1.0f / s;
    bf16x8v o;
    #pragma unroll
    for (int j = 0; j < 8; ++j) o[j] = (bf16)(f[j] * inv);
    *(bf16x8v*)(row + t * 8) = o;
}

// ---------------------------------------------------------------------------
extern "C" void kernel_launch(void* const* d_in, const int* in_sizes, int n_in,
                              void* d_out, int out_size, void* d_ws, size_t ws_size,
                              hipStream_t stream)
{
    const float* x1 = (const float*)d_in[0];
    const float* Wq = (const float*)d_in[1];
    const float* bq = (const float*)d_in[2];
    const float* Wk = (const float*)d_in[3];
    const float* bk = (const float*)d_in[4];
    const float* Wv = (const float*)d_in[5];
    const float* bv = (const float*)d_in[6];
    float* out = (float*)d_out;

    // workspace layout (bf16 elements unless noted)
    bf16* xb     = (bf16*)d_ws;             // 8388608
    bf16* wb     = xb + NX;                 // 3*1048576 (Wq,Wk,Wv rows x 1024)
    bf16* qkb    = wb + 3 * NW;             // 2*8388608 (q then k)
    bf16* vTb    = qkb + 2 * (size_t)NX;    // 8388608 (V^T per batch [D][S])
    bf16* scores = vTb + NX;                // 4*2048*2048
    float* biases = (float*)(scores + 4 * (size_t)SB * SB); // 3072 f32

    // 1. convert inputs to bf16
    convert_kernel<<<dim3(2048), dim3(256), 0, stream>>>(
        x1, Wq, Wk, Wv, bq, bk, bv, xb, wb, biases);

    // 2. fused QKV projection: M=8192, N=3072 (q|k|vT), K=1024; 384 tiles
    gemm8p<0, 256, bf16><<<dim3(384, 1, 1), dim3(512), 0, stream>>>(
        xb, wb, qkb, vTb, biases, 1024, 1024, 12, 0L, 0L, 0L, 1.0f);

    // 3. scores = Q K^T / 32 per batch: M=N=2048, K=1024, z=4; 64 tiles/z
    gemm8p<1, 256, bf16><<<dim3(64, 1, 4), dim3(512), 0, stream>>>(
        qkb, qkb + NX, scores, nullptr, nullptr, SB, DD, 8,
        (long)(SB * DD), (long)(SB * DD), (long)(SB * SB), 1.0f / 32.0f);

    // 4. softmax rows in-place
    softmax_inplace<<<dim3(4 * SB), dim3(256), 0, stream>>>(scores);

    // 5. out = P V per batch: M=2048 (BM=128), N=1024, K=2048, z=4; 64 tiles/z
    gemm8p<2, 128, float><<<dim3(64, 1, 4), dim3(512), 0, stream>>>(
        scores, vTb, out, nullptr, nullptr, DD, SB, 4,
        (long)(SB * SB), (long)(SB * DD), (long)(SB * DD), 1.0f);
}

// Round 5
// 175.923 us; speedup vs baseline: 1.1397x; 1.1397x over previous
//
#include <hip/hip_runtime.h>
#include <cstdint>
#include <cstddef>

using bf16 = __bf16;
typedef float f32x4 __attribute__((ext_vector_type(4)));
typedef __bf16 bf16x8v __attribute__((ext_vector_type(8)));
typedef __bf16 bf16x4v __attribute__((ext_vector_type(4)));

// Problem constants: B=4, S=2048, D=1024
#define NX   8388608      // 4*2048*1024
#define NW   1048576      // 1024*1024
#define SB   2048
#define DD   1024

__device__ __forceinline__ void gload_lds16(const bf16* g, bf16* l) {
    __builtin_amdgcn_global_load_lds(
        (const __attribute__((address_space(1))) void*)(g),
        (__attribute__((address_space(3))) void*)(l), 16, 0, 0);
}

// ---------------------------------------------------------------------------
// Convert fp32 inputs -> bf16 in workspace; copy biases (fp32) contiguous.
// ---------------------------------------------------------------------------
__global__ __launch_bounds__(256)
void convert_kernel(const float* __restrict__ x1,
                    const float* __restrict__ Wq, const float* __restrict__ Wk,
                    const float* __restrict__ Wv,
                    const float* __restrict__ bq, const float* __restrict__ bk,
                    const float* __restrict__ bv,
                    bf16* __restrict__ xb, bf16* __restrict__ wb,
                    float* __restrict__ biases)
{
    const int NX4 = NX / 4;
    const int NW4 = NW / 4;
    const int NMAT = NX4 + 3 * NW4;
    const int total = NMAT + 768;
    for (int i = blockIdx.x * 256 + threadIdx.x; i < total; i += gridDim.x * 256) {
        if (i < NMAT) {
            const float* src; bf16* dst; int j;
            if (i < NX4) { src = x1; dst = xb; j = i; }
            else {
                int w = (i - NX4) / NW4;
                j = (i - NX4) - w * NW4;
                src = (w == 0) ? Wq : (w == 1) ? Wk : Wv;
                dst = wb + (size_t)w * NW;
            }
            float4 f = ((const float4*)src)[j];
            bf16x4v o;
            o[0] = (bf16)f.x; o[1] = (bf16)f.y; o[2] = (bf16)f.z; o[3] = (bf16)f.w;
            ((bf16x4v*)dst)[j] = o;
        } else {
            int j = i - NMAT;
            const float* src = (j < 256) ? bq : (j < 512) ? bk : bv;
            ((float4*)biases)[j] = ((const float4*)src)[j & 255];
        }
    }
}

// ---------------------------------------------------------------------------
// GEMM: C[m][n] = scale * sum_k A[m][k]*B[n][k] (+ epilogue routing)
// A: M x K row-major bf16, B: N x K row-major bf16 (both K-contiguous).
// 128x128 tile, BK=64, 4 waves (2x2 of 64x64), mfma_f32_16x16x32_bf16.
// LDS XOR-swizzle (chunk ^= row&7) via pre-swizzled global source (linear
// LDS dest for global_load_lds) + swizzled ds_read. Conflict-free (round 1/3:
// SQ_LDS_BANK_CONFLICT = 0). XCD-aware bijective block swizzle (nwg%8==0).
// V=0: fused QKV epilogue (bias; col<1024 -> q, <2048 -> k, else v written
//      transposed [b][d][s]).
// V=1: scores epilogue: write P~ = exp(acc*scale - 6) as bf16, and write
//      deterministic partial row-sums pRow[row*32 + bx*2 + wc] (f32).
// V=2: PV epilogue: f32 out multiplied by 1/rowsum (reduced from pRow).
// ---------------------------------------------------------------------------
template<int V, typename OutT>
__global__ __launch_bounds__(256)
void gemm_bt(const bf16* __restrict__ A, const bf16* __restrict__ B,
             OutT* __restrict__ C, bf16* __restrict__ vT,
             const float* __restrict__ bias, float* __restrict__ pRow,
             int N, int K,
             long sAz, long sBz, long sCz, float scale)
{
    __shared__ bf16 lA[128 * 64];
    __shared__ bf16 lB[128 * 64];
    __shared__ float inv[128];   // V==2 only
    const int z = blockIdx.z;
    A += (size_t)z * sAz;
    B += (size_t)z * sBz;
    C += (size_t)z * sCz;
    if constexpr (V == 1 || V == 2) pRow += (size_t)z * (SB * 32);

    // T1: XCD-aware bijective swizzle of the flattened 2D grid
    const int gx = gridDim.x;
    const int nwg = gx * gridDim.y;
    const int orig = (int)blockIdx.y * gx + (int)blockIdx.x;
    const int q8 = nwg >> 3;
    const int tile = (orig & 7) * q8 + (orig >> 3);
    const int bx = tile % gx;
    const int by = tile / gx;

    const int n0 = bx * 128;
    const int m0 = by * 128;
    const int t = threadIdx.x;
    const int lane = t & 63;
    const int wid = t >> 6;
    const int wr = wid >> 1, wc = wid & 1;

    if constexpr (V == 2) {
        // reduce 32 partial row-sums per row -> inv[] in LDS
        if (t < 128) {
            const float4* pr = (const float4*)&pRow[(size_t)(m0 + t) * 32];
            float s = 0.f;
            #pragma unroll
            for (int j = 0; j < 8; ++j) {
                float4 f = pr[j];
                s += f.x + f.y + f.z + f.w;
            }
            inv[t] = 1.0f / s;
        }
        __syncthreads();
    }

    f32x4 acc[4][4];
    #pragma unroll
    for (int m = 0; m < 4; ++m)
        #pragma unroll
        for (int n = 0; n < 4; ++n) acc[m][n] = (f32x4){0.f, 0.f, 0.f, 0.f};

    for (int k0 = 0; k0 < K; k0 += 64) {
        #pragma unroll
        for (int l = 0; l < 4; ++l) {
            const int idx = l * 256 + t;
            const int row = idx >> 3;
            const int c   = idx & 7;
            const int gc  = c ^ (row & 7);   // inverse-swizzled source chunk
            gload_lds16(A + (size_t)(m0 + row) * K + k0 + gc * 8, &lA[idx * 8]);
            gload_lds16(B + (size_t)(n0 + row) * K + k0 + gc * 8, &lB[idx * 8]);
        }
        __syncthreads();
        #pragma unroll
        for (int kk = 0; kk < 2; ++kk) {
            bf16x8v af[4], bfr[4];
            #pragma unroll
            for (int m = 0; m < 4; ++m) {
                const int row = wr * 64 + m * 16 + (lane & 15);
                const int ch  = (kk * 4 + (lane >> 4)) ^ (row & 7);
                af[m] = *(const bf16x8v*)&lA[row * 64 + ch * 8];
            }
            #pragma unroll
            for (int n = 0; n < 4; ++n) {
                const int row = wc * 64 + n * 16 + (lane & 15);
                const int ch  = (kk * 4 + (lane >> 4)) ^ (row & 7);
                bfr[n] = *(const bf16x8v*)&lB[row * 64 + ch * 8];
            }
            #pragma unroll
            for (int m = 0; m < 4; ++m)
                #pragma unroll
                for (int n = 0; n < 4; ++n)
                    acc[m][n] = __builtin_amdgcn_mfma_f32_16x16x32_bf16(
                        af[m], bfr[n], acc[m][n], 0, 0, 0);
        }
        __syncthreads();
    }

    // epilogue: C/D map col=lane&15, row=(lane>>4)*4+reg (m89-verified)
    const int cif = lane & 15;
    const int rif = (lane >> 4) << 2;

    if constexpr (V == 1) {
        float rs[4][4];   // [m][r] partial row sums over this lane's cols
        #pragma unroll
        for (int m = 0; m < 4; ++m)
            #pragma unroll
            for (int r = 0; r < 4; ++r) rs[m][r] = 0.f;

        #pragma unroll
        for (int m = 0; m < 4; ++m) {
            const int gm = m0 + wr * 64 + m * 16 + rif;
            #pragma unroll
            for (int n = 0; n < 4; ++n) {
                const int col = n0 + wc * 64 + n * 16 + cif;
                #pragma unroll
                for (int r = 0; r < 4; ++r) {
                    const float e = __expf(acc[m][n][r] * scale - 6.0f);
                    rs[m][r] += e;
                    C[(size_t)(gm + r) * N + col] = (OutT)e;
                }
            }
        }
        // reduce over the 16 rl-lanes (same rows, different cols)
        #pragma unroll
        for (int m = 0; m < 4; ++m)
            #pragma unroll
            for (int r = 0; r < 4; ++r) {
                #pragma unroll
                for (int msk = 1; msk < 16; msk <<= 1)
                    rs[m][r] += __shfl_xor(rs[m][r], msk);
            }
        if ((lane & 15) == 0) {
            const int slot = bx * 2 + wc;
            #pragma unroll
            for (int m = 0; m < 4; ++m) {
                const int gm = m0 + wr * 64 + m * 16 + rif;
                #pragma unroll
                for (int r = 0; r < 4; ++r)
                    pRow[(size_t)(gm + r) * 32 + slot] = rs[m][r];
            }
        }
    } else {
        #pragma unroll
        for (int m = 0; m < 4; ++m) {
            const int gm = m0 + wr * 64 + m * 16 + rif;
            #pragma unroll
            for (int n = 0; n < 4; ++n) {
                const int col = n0 + wc * 64 + n * 16 + cif;
                if constexpr (V == 0) {
                    const float bb = bias[col];
                    if (col < 1024) {
                        #pragma unroll
                        for (int r = 0; r < 4; ++r)
                            C[(size_t)(gm + r) * 1024 + col] = (OutT)(acc[m][n][r] + bb);
                    } else if (col < 2048) {
                        #pragma unroll
                        for (int r = 0; r < 4; ++r)
                            C[NX + (size_t)(gm + r) * 1024 + (col - 1024)] = (OutT)(acc[m][n][r] + bb);
                    } else {
                        const int batch = gm >> 11, s = gm & 2047, d = col - 2048;
                        bf16x4v pk;
                        #pragma unroll
                        for (int r = 0; r < 4; ++r) pk[r] = (bf16)(acc[m][n][r] + bb);
                        *(bf16x4v*)&vT[((size_t)batch << 21) + ((size_t)d << 11) + s] = pk;
                    }
                } else {  // V == 2: normalize by row sum
                    const int rloc = wr * 64 + m * 16 + rif;
                    #pragma unroll
                    for (int r = 0; r < 4; ++r)
                        C[(size_t)(gm + r) * N + col] = (OutT)(acc[m][n][r] * inv[rloc + r]);
                }
            }
        }
    }
}

// ---------------------------------------------------------------------------
extern "C" void kernel_launch(void* const* d_in, const int* in_sizes, int n_in,
                              void* d_out, int out_size, void* d_ws, size_t ws_size,
                              hipStream_t stream)
{
    const float* x1 = (const float*)d_in[0];
    const float* Wq = (const float*)d_in[1];
    const float* bq = (const float*)d_in[2];
    const float* Wk = (const float*)d_in[3];
    const float* bk = (const float*)d_in[4];
    const float* Wv = (const float*)d_in[5];
    const float* bv = (const float*)d_in[6];
    float* out = (float*)d_out;

    // workspace layout (bf16 elements unless noted)
    bf16* xb     = (bf16*)d_ws;             // 8388608  (x bf16; reused as pRow after QKV)
    bf16* wb     = xb + NX;                 // 3*1048576 (Wq,Wk,Wv rows x 1024)
    bf16* qkb    = wb + 3 * NW;             // 2*8388608 (q then k)
    bf16* vTb    = qkb + 2 * (size_t)NX;    // 8388608 (V^T per batch [D][S])
    bf16* scores = vTb + NX;                // 4*2048*2048 (P~ after scores pass)
    float* biases = (float*)(scores + 4 * (size_t)SB * SB); // 3072 f32
    float* partial = (float*)xb;            // [4][2048][32] f32 = 1 MB (xb dead post-QKV)

    // 1. convert inputs to bf16
    convert_kernel<<<dim3(2048), dim3(256), 0, stream>>>(
        x1, Wq, Wk, Wv, bq, bk, bv, xb, wb, biases);

    // 2. fused QKV projection: M=8192, N=3072 (q|k|vT), K=1024
    gemm_bt<0, bf16><<<dim3(24, 64, 1), dim3(256), 0, stream>>>(
        xb, wb, qkb, vTb, biases, nullptr, 1024, 1024, 0L, 0L, 0L, 1.0f);

    // 3. P~ = exp(QK^T/32 - 6) per batch + partial row sums: M=N=2048, K=1024
    gemm_bt<1, bf16><<<dim3(16, 16, 4), dim3(256), 0, stream>>>(
        qkb, qkb + NX, scores, nullptr, nullptr, partial, SB, DD,
        (long)(SB * DD), (long)(SB * DD), (long)(SB * SB), 1.0f / 32.0f);

    // 4. out = (P~ V) / rowsum per batch: M=2048, N=1024, K=2048, f32 out
    gemm_bt<2, float><<<dim3(8, 16, 4), dim3(256), 0, stream>>>(
        scores, vTb, out, nullptr, nullptr, partial, DD, SB,
        (long)(SB * SB), (long)(SB * DD), (long)(SB * DD), 1.0f);
}

// Round 6
// 174.894 us; speedup vs baseline: 1.1464x; 1.0059x over previous
//
#include <hip/hip_runtime.h>
#include <cstdint>
#include <cstddef>

using bf16 = __bf16;
typedef float f32x4 __attribute__((ext_vector_type(4)));
typedef __bf16 bf16x8v __attribute__((ext_vector_type(8)));
typedef __bf16 bf16x4v __attribute__((ext_vector_type(4)));

// Problem constants: B=4, S=2048, D=1024
#define NX   8388608      // 4*2048*1024
#define NW   1048576      // 1024*1024
#define SB   2048
#define DD   1024

#define VMCNT(n) asm volatile("s_waitcnt vmcnt(" #n ")" ::: "memory")

__device__ __forceinline__ void gload_lds16(const bf16* g, bf16* l) {
    __builtin_amdgcn_global_load_lds(
        (const __attribute__((address_space(1))) void*)(g),
        (__attribute__((address_space(3))) void*)(l), 16, 0, 0);
}

// ---------------------------------------------------------------------------
// Convert fp32 inputs -> bf16 in workspace; copy biases (fp32) contiguous.
// ---------------------------------------------------------------------------
__global__ __launch_bounds__(256)
void convert_kernel(const float* __restrict__ x1,
                    const float* __restrict__ Wq, const float* __restrict__ Wk,
                    const float* __restrict__ Wv,
                    const float* __restrict__ bq, const float* __restrict__ bk,
                    const float* __restrict__ bv,
                    bf16* __restrict__ xb, bf16* __restrict__ wb,
                    float* __restrict__ biases)
{
    const int NX4 = NX / 4;
    const int NW4 = NW / 4;
    const int NMAT = NX4 + 3 * NW4;
    const int total = NMAT + 768;
    for (int i = blockIdx.x * 256 + threadIdx.x; i < total; i += gridDim.x * 256) {
        if (i < NMAT) {
            const float* src; bf16* dst; int j;
            if (i < NX4) { src = x1; dst = xb; j = i; }
            else {
                int w = (i - NX4) / NW4;
                j = (i - NX4) - w * NW4;
                src = (w == 0) ? Wq : (w == 1) ? Wk : Wv;
                dst = wb + (size_t)w * NW;
            }
            float4 f = ((const float4*)src)[j];
            bf16x4v o;
            o[0] = (bf16)f.x; o[1] = (bf16)f.y; o[2] = (bf16)f.z; o[3] = (bf16)f.w;
            ((bf16x4v*)dst)[j] = o;
        } else {
            int j = i - NMAT;
            const float* src = (j < 256) ? bq : (j < 512) ? bk : bv;
            ((float4*)biases)[j] = ((const float4*)src)[j & 255];
        }
    }
}

// ---------------------------------------------------------------------------
// 2-phase 128x128 GEMM (m97 structure) — QKV only.
// C[m][n] = sum_k A[m][k]*B[n][k] + bias[n]; col routes q / k / v-transposed.
// Conflict-free XOR swizzle; T1 XCD block swizzle. 3 blocks/CU at 32KB LDS.
// ---------------------------------------------------------------------------
__global__ __launch_bounds__(256)
void gemm_qkv(const bf16* __restrict__ A, const bf16* __restrict__ B,
              bf16* __restrict__ C, bf16* __restrict__ vT,
              const float* __restrict__ bias, int K)
{
    __shared__ bf16 lA[128 * 64];
    __shared__ bf16 lB[128 * 64];

    const int gx = gridDim.x;
    const int nwg = gx * gridDim.y;
    const int orig = (int)blockIdx.y * gx + (int)blockIdx.x;
    const int q8 = nwg >> 3;
    const int tile = (orig & 7) * q8 + (orig >> 3);
    const int bx = tile % gx;
    const int by = tile / gx;

    const int n0 = bx * 128;
    const int m0 = by * 128;
    const int t = threadIdx.x;
    const int lane = t & 63;
    const int wid = t >> 6;
    const int wr = wid >> 1, wc = wid & 1;

    f32x4 acc[4][4];
    #pragma unroll
    for (int m = 0; m < 4; ++m)
        #pragma unroll
        for (int n = 0; n < 4; ++n) acc[m][n] = (f32x4){0.f, 0.f, 0.f, 0.f};

    for (int k0 = 0; k0 < K; k0 += 64) {
        #pragma unroll
        for (int l = 0; l < 4; ++l) {
            const int idx = l * 256 + t;
            const int row = idx >> 3;
            const int c   = idx & 7;
            const int gc  = c ^ (row & 7);
            gload_lds16(A + (size_t)(m0 + row) * K + k0 + gc * 8, &lA[idx * 8]);
            gload_lds16(B + (size_t)(n0 + row) * K + k0 + gc * 8, &lB[idx * 8]);
        }
        __syncthreads();
        #pragma unroll
        for (int kk = 0; kk < 2; ++kk) {
            bf16x8v af[4], bfr[4];
            #pragma unroll
            for (int m = 0; m < 4; ++m) {
                const int row = wr * 64 + m * 16 + (lane & 15);
                const int ch  = (kk * 4 + (lane >> 4)) ^ (row & 7);
                af[m] = *(const bf16x8v*)&lA[row * 64 + ch * 8];
            }
            #pragma unroll
            for (int n = 0; n < 4; ++n) {
                const int row = wc * 64 + n * 16 + (lane & 15);
                const int ch  = (kk * 4 + (lane >> 4)) ^ (row & 7);
                bfr[n] = *(const bf16x8v*)&lB[row * 64 + ch * 8];
            }
            #pragma unroll
            for (int m = 0; m < 4; ++m)
                #pragma unroll
                for (int n = 0; n < 4; ++n)
                    acc[m][n] = __builtin_amdgcn_mfma_f32_16x16x32_bf16(
                        af[m], bfr[n], acc[m][n], 0, 0, 0);
        }
        __syncthreads();
    }

    const int cif = lane & 15;
    const int rif = (lane >> 4) << 2;
    #pragma unroll
    for (int m = 0; m < 4; ++m) {
        const int gm = m0 + wr * 64 + m * 16 + rif;
        #pragma unroll
        for (int n = 0; n < 4; ++n) {
            const int col = n0 + wc * 64 + n * 16 + cif;
            const float bb = bias[col];
            if (col < 1024) {
                #pragma unroll
                for (int r = 0; r < 4; ++r)
                    C[(size_t)(gm + r) * 1024 + col] = (bf16)(acc[m][n][r] + bb);
            } else if (col < 2048) {
                #pragma unroll
                for (int r = 0; r < 4; ++r)
                    C[NX + (size_t)(gm + r) * 1024 + (col - 1024)] = (bf16)(acc[m][n][r] + bb);
            } else {
                const int batch = gm >> 11, s = gm & 2047, d = col - 2048;
                bf16x4v pk;
                #pragma unroll
                for (int r = 0; r < 4; ++r) pk[r] = (bf16)(acc[m][n][r] + bb);
                *(bf16x4v*)&vT[((size_t)batch << 21) + ((size_t)d << 11) + s] = pk;
            }
        }
    }
}

// ---------------------------------------------------------------------------
// 8-phase GEMM (BM x 256 tile, BK=64 as two 32-slices, 8 waves, 512 thr,
// counted vmcnt, 2 barriers/tile) — validated round 4. Epilogues:
// V=1: scores — write P~ = exp(acc*scale - 6) bf16 + deterministic partial
//      row-sums pRow[row*32 + bx*4 + wc].
// V=2: PV — f32 out scaled by 1/rowsum (reduced from pRow at block entry).
// ---------------------------------------------------------------------------
template<int V, int BM, typename OutT>
__global__ __launch_bounds__(512, 2)
void gemm8p(const bf16* __restrict__ A, const bf16* __restrict__ B,
            OutT* __restrict__ C, float* __restrict__ pRow,
            int N, int K, int NXT,
            long sA, long sB, long sC, float scale)
{
    constexpr int MF = BM / 32;
    constexpr int MH = MF / 2;
    constexpr int LA = BM / 128;

    __shared__ bf16 shA[2][2][BM * 32];
    __shared__ bf16 shB[2][2][256 * 32];
    __shared__ float inv[128];   // V==2 only

    const int z = blockIdx.z;
    A += (size_t)z * sA; B += (size_t)z * sB; C += (size_t)z * sC;
    pRow += (size_t)z * (SB * 32);

    const int nwg = gridDim.x;
    const int q8 = nwg >> 3;
    const int tile = ((int)blockIdx.x & 7) * q8 + ((int)blockIdx.x >> 3);
    const int bx = tile % NXT, by = tile / NXT;
    const int n0 = bx * 256, m0 = by * BM;

    const int tid = threadIdx.x;
    const int lane = tid & 63, wid = tid >> 6;
    const int wr = wid >> 2, wc = wid & 3;

    if constexpr (V == 2) {
        if (tid < BM) {
            const float4* pr = (const float4*)&pRow[(size_t)(m0 + tid) * 32];
            float s = 0.f;
            #pragma unroll
            for (int j = 0; j < 8; ++j) {
                float4 f = pr[j];
                s += f.x + f.y + f.z + f.w;
            }
            inv[tid] = 1.0f / s;
        }
        __syncthreads();
    }

    const bf16* Ag = A + (size_t)m0 * K;
    const bf16* Bg = B + (size_t)n0 * K;

    auto chunkoff = [&](int ci) {
        const int line = ci >> 3;
        const int su = (ci & 7) ^ (line & 7);
        const int r = 2 * line + (su >> 2);
        const int c = su & 3;
        return r * K + c * 8;
    };
    const int o0 = chunkoff(tid);
    const int o1 = chunkoff(512 + tid);

    const int rl = lane & 15, lg = lane >> 4;
    const int rp = rl & 1, rh = rl >> 1;
    const int lA0 = wr * (BM / 4) + rh;
    const int offA = lA0 * 64 + ((((rp << 2) | lg) ^ (lA0 & 7)) << 3);
    const int lB0 = wc * 32 + rh;
    const int offB = lB0 * 64 + ((((rp << 2) | lg) ^ (lB0 & 7)) << 3);

    f32x4 acc[MF][4];
    #pragma unroll
    for (int m = 0; m < MF; ++m)
        #pragma unroll
        for (int n = 0; n < 4; ++n) acc[m][n] = (f32x4){0.f, 0.f, 0.f, 0.f};

    const int NT = K >> 6;

    auto stageA = [&](const bf16* gk, bf16* l) {
        gload_lds16(gk + o0, l + tid * 8);
        if constexpr (LA == 2) gload_lds16(gk + o1, l + (512 + tid) * 8);
    };
    auto stageB = [&](const bf16* gk, bf16* l) {
        gload_lds16(gk + o0, l + tid * 8);
        gload_lds16(gk + o1, l + (512 + tid) * 8);
    };

    stageA(Ag,      &shA[0][0][0]);
    stageB(Bg,      &shB[0][0][0]);
    stageA(Ag + 32, &shA[0][1][0]);
    stageB(Bg + 32, &shB[0][1][0]);
    stageA(Ag + 64, &shA[1][0][0]);
    stageB(Bg + 64, &shB[1][0][0]);

    for (int t = 0; t < NT; ++t) {
        const int buf = t & 1;
        const bool nl  = (t + 1 < NT);
        const bool nl2 = (t + 2 < NT);
        bf16x8v bfr[4], af[MH];

        // p0: ks0 mh0
        if (nl) { if constexpr (LA == 2) VMCNT(8); else VMCNT(6); }
        else    { if constexpr (LA == 2) VMCNT(4); else VMCNT(3); }
        __builtin_amdgcn_s_barrier();
        if (nl) stageA(Ag + (t + 1) * 64 + 32, &shA[buf ^ 1][1][0]);
        {
            const bf16* pb = &shB[buf][0][offB];
            #pragma unroll
            for (int n = 0; n < 4; ++n) bfr[n] = *(const bf16x8v*)(pb + n * 512);
            const bf16* pa = &shA[buf][0][offA];
            #pragma unroll
            for (int i = 0; i < MH; ++i) af[i] = *(const bf16x8v*)(pa + i * 512);
        }
        asm volatile("s_waitcnt lgkmcnt(0)" ::: "memory");
        __builtin_amdgcn_sched_barrier(0);
        __builtin_amdgcn_s_setprio(1);
        #pragma unroll
        for (int i = 0; i < MH; ++i)
            #pragma unroll
            for (int n = 0; n < 4; ++n)
                acc[i][n] = __builtin_amdgcn_mfma_f32_16x16x32_bf16(af[i], bfr[n], acc[i][n], 0, 0, 0);
        __builtin_amdgcn_s_setprio(0);

        // p1: ks0 mh1
        if (nl) stageB(Bg + (t + 1) * 64 + 32, &shB[buf ^ 1][1][0]);
        {
            const bf16* pa = &shA[buf][0][offA];
            #pragma unroll
            for (int i = 0; i < MH; ++i) af[i] = *(const bf16x8v*)(pa + (MH + i) * 512);
        }
        asm volatile("s_waitcnt lgkmcnt(0)" ::: "memory");
        __builtin_amdgcn_sched_barrier(0);
        __builtin_amdgcn_s_setprio(1);
        #pragma unroll
        for (int i = 0; i < MH; ++i)
            #pragma unroll
            for (int n = 0; n < 4; ++n)
                acc[MH + i][n] = __builtin_amdgcn_mfma_f32_16x16x32_bf16(af[i], bfr[n], acc[MH + i][n], 0, 0, 0);
        __builtin_amdgcn_s_setprio(0);

        // p2: ks1 mh0
        if (nl) { if constexpr (LA == 2) VMCNT(8); else VMCNT(6); }
        else    VMCNT(0);
        __builtin_amdgcn_s_barrier();
        if (nl2) stageA(Ag + (t + 2) * 64, &shA[buf][0][0]);
        {
            const bf16* pb = &shB[buf][1][offB];
            #pragma unroll
            for (int n = 0; n < 4; ++n) bfr[n] = *(const bf16x8v*)(pb + n * 512);
            const bf16* pa = &shA[buf][1][offA];
            #pragma unroll
            for (int i = 0; i < MH; ++i) af[i] = *(const bf16x8v*)(pa + i * 512);
        }
        asm volatile("s_waitcnt lgkmcnt(0)" ::: "memory");
        __builtin_amdgcn_sched_barrier(0);
        __builtin_amdgcn_s_setprio(1);
        #pragma unroll
        for (int i = 0; i < MH; ++i)
            #pragma unroll
            for (int n = 0; n < 4; ++n)
                acc[i][n] = __builtin_amdgcn_mfma_f32_16x16x32_bf16(af[i], bfr[n], acc[i][n], 0, 0, 0);
        __builtin_amdgcn_s_setprio(0);

        // p3: ks1 mh1
        if (nl2) stageB(Bg + (t + 2) * 64, &shB[buf][0][0]);
        {
            const bf16* pa = &shA[buf][1][offA];
            #pragma unroll
            for (int i = 0; i < MH; ++i) af[i] = *(const bf16x8v*)(pa + (MH + i) * 512);
        }
        asm volatile("s_waitcnt lgkmcnt(0)" ::: "memory");
        __builtin_amdgcn_sched_barrier(0);
        __builtin_amdgcn_s_setprio(1);
        #pragma unroll
        for (int i = 0; i < MH; ++i)
            #pragma unroll
            for (int n = 0; n < 4; ++n)
                acc[MH + i][n] = __builtin_amdgcn_mfma_f32_16x16x32_bf16(af[i], bfr[n], acc[MH + i][n], 0, 0, 0);
        __builtin_amdgcn_s_setprio(0);
    }

    // epilogue
    const int ci = rl;
    const int ri = lg << 2;
    if constexpr (V == 1) {
        float rs[MF][4];
        #pragma unroll
        for (int m = 0; m < MF; ++m)
            #pragma unroll
            for (int r = 0; r < 4; ++r) rs[m][r] = 0.f;

        #pragma unroll
        for (int m = 0; m < MF; ++m) {
            const int gm = m0 + wr * (BM / 2) + m * 16 + ri;
            #pragma unroll
            for (int n = 0; n < 4; ++n) {
                const int col = n0 + wc * 64 + n * 16 + ci;
                #pragma unroll
                for (int r = 0; r < 4; ++r) {
                    const float e = __expf(acc[m][n][r] * scale - 6.0f);
                    rs[m][r] += e;
                    C[(size_t)(gm + r) * N + col] = (OutT)e;
                }
            }
        }
        #pragma unroll
        for (int m = 0; m < MF; ++m)
            #pragma unroll
            for (int r = 0; r < 4; ++r) {
                #pragma unroll
                for (int msk = 1; msk < 16; msk <<= 1)
                    rs[m][r] += __shfl_xor(rs[m][r], msk);
            }
        if (rl == 0) {
            const int slot = bx * 4 + wc;
            #pragma unroll
            for (int m = 0; m < MF; ++m) {
                const int gm = m0 + wr * (BM / 2) + m * 16 + ri;
                #pragma unroll
                for (int r = 0; r < 4; ++r)
                    pRow[(size_t)(gm + r) * 32 + slot] = rs[m][r];
            }
        }
    } else {
        #pragma unroll
        for (int m = 0; m < MF; ++m) {
            const int gm = m0 + wr * (BM / 2) + m * 16 + ri;
            const int rloc = wr * (BM / 2) + m * 16 + ri;
            #pragma unroll
            for (int n = 0; n < 4; ++n) {
                const int col = n0 + wc * 64 + n * 16 + ci;
                #pragma unroll
                for (int r = 0; r < 4; ++r)
                    C[(size_t)(gm + r) * N + col] = (OutT)(acc[m][n][r] * inv[rloc + r]);
            }
        }
    }
}

// ---------------------------------------------------------------------------
extern "C" void kernel_launch(void* const* d_in, const int* in_sizes, int n_in,
                              void* d_out, int out_size, void* d_ws, size_t ws_size,
                              hipStream_t stream)
{
    const float* x1 = (const float*)d_in[0];
    const float* Wq = (const float*)d_in[1];
    const float* bq = (const float*)d_in[2];
    const float* Wk = (const float*)d_in[3];
    const float* bk = (const float*)d_in[4];
    const float* Wv = (const float*)d_in[5];
    const float* bv = (const float*)d_in[6];
    float* out = (float*)d_out;

    // workspace layout (bf16 elements unless noted)
    bf16* xb     = (bf16*)d_ws;             // x bf16; reused as pRow after QKV
    bf16* wb     = xb + NX;                 // 3*1048576
    bf16* qkb    = wb + 3 * NW;             // 2*8388608 (q then k)
    bf16* vTb    = qkb + 2 * (size_t)NX;    // 8388608 (V^T per batch [D][S])
    bf16* scores = vTb + NX;                // 4*2048*2048 (P~)
    float* biases = (float*)(scores + 4 * (size_t)SB * SB); // 3072 f32
    float* partial = (float*)xb;            // [4][2048][32] f32 (xb dead post-QKV)

    // 1. convert inputs to bf16
    convert_kernel<<<dim3(2048), dim3(256), 0, stream>>>(
        x1, Wq, Wk, Wv, bq, bk, bv, xb, wb, biases);

    // 2. fused QKV projection (2-phase 128^2): M=8192, N=3072, K=1024
    gemm_qkv<<<dim3(24, 64, 1), dim3(256), 0, stream>>>(
        xb, wb, qkb, vTb, biases, 1024);

    // 3. P~ = exp(QK^T/32 - 6) + partials (8-phase 256^2): 256 blocks
    gemm8p<1, 256, bf16><<<dim3(64, 1, 4), dim3(512), 0, stream>>>(
        qkb, qkb + NX, scores, partial, SB, DD, 8,
        (long)(SB * DD), (long)(SB * DD), (long)(SB * SB), 1.0f / 32.0f);

    // 4. out = (P~ V)/rowsum (8-phase 128x256): 256 blocks, f32 out
    gemm8p<2, 128, float><<<dim3(64, 1, 4), dim3(512), 0, stream>>>(
        scores, vTb, out, partial, DD, SB, 4,
        (long)(SB * SB), (long)(SB * DD), (long)(SB * DD), 1.0f);
}